// Round 16
// baseline (166.751 us; speedup 1.0000x reference)
//
#include <hip/hip_runtime.h>
#include <math.h>

#define C_DIM 256
#define N_DIM 4096
#define NHEAD 8

using bf16x8 = __attribute__((ext_vector_type(8))) short;   // 8 bf16 = 4 VGPRs
using f32x16 = __attribute__((ext_vector_type(16))) float;  // 32x32 MFMA acc
using f32x4v = __attribute__((ext_vector_type(4))) float;   // clang vec for NT store

__device__ __forceinline__ short f32_to_bf16(float a) {
    return (short)((__float_as_uint(a) + 0x8000u) >> 16);
}
__device__ __forceinline__ float bf16_to_f32(unsigned short u) {
    return __uint_as_float(((unsigned)u) << 16);
}
// truncating pack: lo = hi16(a), hi = hi16(b)
__device__ __forceinline__ unsigned pack_trunc(float a, float b) {
    return __builtin_amdgcn_perm(__float_as_uint(b), __float_as_uint(a), 0x07060302u);
}
// rounded pack: lo = bf16_rnd(a), hi = bf16_rnd(b)  (same bits as f32_to_bf16)
__device__ __forceinline__ unsigned pack_rnd(float a, float b) {
    return __builtin_amdgcn_perm(__float_as_uint(b) + 0x8000u,
                                 __float_as_uint(a) + 0x8000u, 0x07060302u);
}

// Fragment-order ("swizzled") layout for 256-col planes, index in shorts.
// Per 32-row tile: [16 kc][2 q2][32 row][8 c]
__device__ __forceinline__ int SWZ(int m, int c) {
    return (m >> 5) * 8192 + (c >> 4) * 512 + ((c >> 3) & 1) * 256 + (m & 31) * 8 + (c & 7);
}

// ---------------------------------------------------------------------------
// prep: z<4 -> transpose query/key [c][n] fp32 -> swizzled bf16 [n][c] planes
//       z==4 -> convert 4 weight planes fp32 -> swizzled bf16
// ---------------------------------------------------------------------------
__global__ __launch_bounds__(256) void prep(
    const float* __restrict__ query, const float* __restrict__ key,
    const float* __restrict__ qw, const float* __restrict__ kw,
    const float* __restrict__ vw, const float* __restrict__ ow,
    short* __restrict__ Qx, short* __restrict__ Kx, short* __restrict__ Wsw)
{
    const int t = threadIdx.x;
    if (blockIdx.z == 4) {
        const int p = blockIdx.y;
        const float* src = (p == 0) ? qw : (p == 1) ? kw : (p == 2) ? vw : ow;
        const int idx = (blockIdx.x * 256 + t) * 4;
        const int o = idx >> 8, c = idx & 255;
        float4 v = *(const float4*)&src[idx];
        short* dst = Wsw + p * 65536 + SWZ(o, c);
        dst[0] = f32_to_bf16(v.x); dst[1] = f32_to_bf16(v.y);
        dst[2] = f32_to_bf16(v.z); dst[3] = f32_to_bf16(v.w);
        return;
    }
    __shared__ unsigned Ts32[32][33];   // [n-local][c-pair], pitch 33 words
    const int z = blockIdx.z;
    const float* in = (z < 2) ? query : key;
    short* out = ((z < 2) ? Qx : Kx) + (size_t)(z & 1) * N_DIM * C_DIM;
    const size_t ibase = (size_t)(z & 1) * C_DIM * N_DIM;
    const int n0 = blockIdx.x * 64, c0 = blockIdx.y * 64;
    const int cp = t >> 3, ng = t & 7;   // c-pair 0..31, n-group 0..7

#pragma unroll
    for (int h2 = 0; h2 < 2; ++h2) {
        const int nb = h2 * 32 + ng * 4;
        float4 a = *(const float4*)&in[ibase + (size_t)(c0 + 2 * cp) * N_DIM + n0 + nb];
        float4 b = *(const float4*)&in[ibase + (size_t)(c0 + 2 * cp + 1) * N_DIM + n0 + nb];
        Ts32[ng * 4 + 0][cp] = pack_rnd(a.x, b.x);
        Ts32[ng * 4 + 1][cp] = pack_rnd(a.y, b.y);
        Ts32[ng * 4 + 2][cp] = pack_rnd(a.z, b.z);
        Ts32[ng * 4 + 3][cp] = pack_rnd(a.w, b.w);
        __syncthreads();
        const int nl = t >> 3, cg = t & 7;
        uint4 val;
        val.x = Ts32[nl][cg * 4 + 0];
        val.y = Ts32[nl][cg * 4 + 1];
        val.z = Ts32[nl][cg * 4 + 2];
        val.w = Ts32[nl][cg * 4 + 3];
        *(uint4*)&out[SWZ(n0 + h2 * 32 + nl, c0 + cg * 8)] = val;
        __syncthreads();
    }
}

// ---------------------------------------------------------------------------
// QKV projection (byte-identical to r12-r14): operand-swapped C-tiles, b64
// fragment-order epilogue stores.
// ---------------------------------------------------------------------------
__global__ __launch_bounds__(256) void qkv_gemm(
    const short* __restrict__ Wsw, const short* __restrict__ Qx,
    const short* __restrict__ Kx,
    const float* __restrict__ q_b, const float* __restrict__ k_b,
    const float* __restrict__ v_b,
    short* __restrict__ Qt, short* __restrict__ Kt, short* __restrict__ Vt,
    float qscale)
{
    const int t = threadIdx.x, w = t >> 6, lane = t & 63;
    const int q2 = lane >> 5, l31 = lane & 31;
    const int proj = blockIdx.z >> 1, b = blockIdx.z & 1;
    const int n0 = blockIdx.x * 64 + (w >> 1) * 32;
    const int o0 = blockIdx.y * 64 + (w & 1) * 32;
    const short* X = ((proj == 0) ? Qx : Kx) + (size_t)b * N_DIM * C_DIM;
    const short* W = Wsw + proj * 65536;
    const float* bias = (proj == 0) ? q_b : (proj == 1) ? k_b : v_b;
    const int xbase = (n0 >> 5) * 8192 + q2 * 256 + l31 * 8;
    const int wbase = (o0 >> 5) * 8192 + q2 * 256 + l31 * 8;

    f32x16 acc;
#pragma unroll
    for (int r = 0; r < 16; ++r) acc[r] = 0.f;

#pragma unroll 4
    for (int kc = 0; kc < C_DIM; kc += 16) {
        bf16x8 xf = *(const bf16x8*)&X[xbase + (kc >> 4) * 512];
        bf16x8 wf = *(const bf16x8*)&W[wbase + (kc >> 4) * 512];
        if (proj == 2)
            acc = __builtin_amdgcn_mfma_f32_32x32x16_bf16(xf, wf, acc, 0, 0, 0);
        else
            acc = __builtin_amdgcn_mfma_f32_32x32x16_bf16(wf, xf, acc, 0, 0, 0);
    }

    const int head = o0 >> 5;
    const size_t fbase = (size_t)(n0 >> 5) * 1024 + l31 * 8 + 4 * q2;
    if (proj < 2) {
        short* OH = ((proj == 0) ? Qt : Kt) + (size_t)(b * NHEAD + head) * N_DIM * 32;
        const float sc = (proj == 0) ? qscale : 1.f;
#pragma unroll
        for (int g = 0; g < 4; ++g) {
            float4 bv = *(const float4*)&bias[o0 + 8 * g + 4 * q2];
            uint2 st;
            st.x = pack_rnd((acc[4 * g + 0] + bv.x) * sc, (acc[4 * g + 1] + bv.y) * sc);
            st.y = pack_rnd((acc[4 * g + 2] + bv.z) * sc, (acc[4 * g + 3] + bv.w) * sc);
            *(uint2*)&OH[fbase + (g >> 1) * 512 + (g & 1) * 256] = st;
        }
    } else {
        short* VH = Vt + (size_t)(b * NHEAD + head) * N_DIM * 32;
        const float bi = bias[o0 + l31];
#pragma unroll
        for (int g = 0; g < 4; ++g) {
            uint2 st;
            st.x = pack_rnd(acc[4 * g + 0] + bi, acc[4 * g + 1] + bi);
            st.y = pack_rnd(acc[4 * g + 2] + bi, acc[4 * g + 3] + bi);
            *(uint2*)&VH[fbase + (g >> 1) * 512 + (g & 1) * 256] = st;
        }
    }
}

// ---------------------------------------------------------------------------
// Flash attention: r14 main loop with the P^T routing rebuilt on
// v_permlane32_swap_b32 (gfx950): one swap per register pair replaces
// shfl_xor(32) + two cndmask-selected words. Lane algebra:
//   swap(u0, u2): u0' = {u0_lo, u2_lo} = f0.x ; u2' = {u0_hi, u2_hi} = f0.z
// Bit-identical P fragments, 24 -> 4 instructions per iteration.
// ---------------------------------------------------------------------------
__global__ __launch_bounds__(256) void flash_mfma(
    const short* __restrict__ Qt, const short* __restrict__ Kt,
    const short* __restrict__ Vt, short* __restrict__ Opart,
    float* __restrict__ lpart)
{
    const int n0 = blockIdx.x * 128;
    const int h  = blockIdx.y;
    const int z  = blockIdx.z;
    const int b  = z >> 2, s = z & 3;
    const int CHUNK = N_DIM / 4;
    const int t = threadIdx.x, w = t >> 6, lane = t & 63;
    const int q2 = lane >> 5, l31 = lane & 31;
    const int q  = n0 + w * 32 + l31;
    const int bhp = b * NHEAD + h;
    const size_t hb = (size_t)bhp * N_DIM * 32;

    const int qoff = (q >> 5) * 1024 + q2 * 256 + (q & 31) * 8;
    bf16x8 Qf0 = *(const bf16x8*)&Qt[hb + qoff];
    bf16x8 Qf1 = *(const bf16x8*)&Qt[hb + qoff + 512];

    const f32x16 zc = {};   // hoisted zero-C (constant across the K loop)

    int off = ((s * CHUNK) >> 5) * 1024 + q2 * 256 + l31 * 8;
    bf16x8 Kc0 = *(const bf16x8*)&Kt[hb + off];
    bf16x8 Kc1 = *(const bf16x8*)&Kt[hb + off + 512];
    bf16x8 Vc0 = *(const bf16x8*)&Vt[hb + off];
    bf16x8 Vc1 = *(const bf16x8*)&Vt[hb + off + 512];
    off += 1024;

    f32x16 Of;
#pragma unroll
    for (int r = 0; r < 16; ++r) Of[r] = 0.f;
    float ls = 0.f;

    for (int it = 0; it < CHUNK / 32; ++it) {
        bf16x8 Kn0 = *(const bf16x8*)&Kt[hb + off];
        bf16x8 Kn1 = *(const bf16x8*)&Kt[hb + off + 512];
        bf16x8 Vn0 = *(const bf16x8*)&Vt[hb + off];
        bf16x8 Vn1 = *(const bf16x8*)&Vt[hb + off + 512];
        off += 1024;

        f32x16 acc = __builtin_amdgcn_mfma_f32_32x32x16_bf16(Kc0, Qf0, zc, 0, 0, 0);
        acc = __builtin_amdgcn_mfma_f32_32x32x16_bf16(Kc1, Qf1, acc, 0, 0, 0);

        float p[16];
#pragma unroll
        for (int r = 0; r < 16; ++r) { p[r] = __builtin_amdgcn_exp2f(acc[r]); ls += p[r]; }

        unsigned u[8];
#pragma unroll
        for (int g = 0; g < 8; ++g) u[g] = pack_trunc(p[2 * g], p[2 * g + 1]);

        // half-lane swaps: (0,2) (1,3) (4,6) (5,7) -> P^T B-frag words in place
        asm volatile("v_permlane32_swap_b32 %0, %1" : "+v"(u[0]), "+v"(u[2]));
        asm volatile("v_permlane32_swap_b32 %0, %1" : "+v"(u[1]), "+v"(u[3]));
        asm volatile("v_permlane32_swap_b32 %0, %1" : "+v"(u[4]), "+v"(u[6]));
        asm volatile("v_permlane32_swap_b32 %0, %1" : "+v"(u[5]), "+v"(u[7]));

        uint4 f0, f1;
        f0.x = u[0]; f0.y = u[1]; f0.z = u[2]; f0.w = u[3];
        f1.x = u[4]; f1.y = u[5]; f1.z = u[6]; f1.w = u[7];
        bf16x8 Pf0 = __builtin_bit_cast(bf16x8, f0);
        bf16x8 Pf1 = __builtin_bit_cast(bf16x8, f1);

        Of = __builtin_amdgcn_mfma_f32_32x32x16_bf16(Vc0, Pf0, Of, 0, 0, 0);
        Of = __builtin_amdgcn_mfma_f32_32x32x16_bf16(Vc1, Pf1, Of, 0, 0, 0);

        Kc0 = Kn0; Kc1 = Kn1; Vc0 = Vn0; Vc1 = Vn1;
    }

    ls += __shfl_xor(ls, 32, 64);

    // Opart in fragment order: reg group g holds d = 8g+4q2 .. +3 for row q.
    const size_t obase = (size_t)(s * 16 + bhp) * (N_DIM * 32)
                       + (size_t)(q >> 5) * 1024 + l31 * 8 + 4 * q2;
#pragma unroll
    for (int g = 0; g < 4; ++g) {
        uint2 st;
        st.x = pack_rnd(Of[4 * g + 0], Of[4 * g + 1]);
        st.y = pack_rnd(Of[4 * g + 2], Of[4 * g + 3]);
        *(uint2*)&Opart[obase + (g >> 1) * 512 + (g & 1) * 256] = st;
    }
    lpart[(size_t)(s * 16 + bhp) * N_DIM + q] = ls;
}

// ---------------------------------------------------------------------------
// Out projection with fused split-K combine + fused GroupNorm partial stats
// (byte-identical to r14).
// ---------------------------------------------------------------------------
__global__ __launch_bounds__(256) void out_gemm(
    const short* __restrict__ OWsw, const short* __restrict__ Opart,
    const float* __restrict__ lpart, const float* __restrict__ ob,
    const float* __restrict__ query, short* __restrict__ y16,
    float* __restrict__ pstats)
{
    const int t = threadIdx.x, w = t >> 6, lane = t & 63;
    const int q2 = lane >> 5, l31 = lane & 31;
    const int n0 = blockIdx.x * 32, b = blockIdx.y, oz = blockIdx.z;
    const int o0 = oz * 128 + w * 32;
    const int n = n0 + l31;

    float linv[8];
#pragma unroll
    for (int h = 0; h < 8; ++h) {
        float s = 0.f;
#pragma unroll
        for (int s4 = 0; s4 < 4; ++s4)
            s += lpart[(size_t)(s4 * 16 + b * 8 + h) * N_DIM + n];
        linv[h] = 1.f / s;
    }

    const int abase = (o0 >> 5) * 8192 + q2 * 256 + l31 * 8;
    const size_t SSTR = (size_t)16 * N_DIM * 32;

    f32x16 acc;
#pragma unroll
    for (int r = 0; r < 16; ++r) acc[r] = 0.f;

#pragma unroll
    for (int kc = 0; kc < 16; ++kc) {
        const int head = kc >> 1;
        const size_t base0 = (size_t)(b * 8 + head) * (N_DIM * 32)
                           + (size_t)(n0 >> 5) * 1024 + (kc & 1) * 512
                           + q2 * 256 + l31 * 8;
        bf16x8 p0 = *(const bf16x8*)&Opart[base0];
        bf16x8 p1 = *(const bf16x8*)&Opart[base0 + SSTR];
        bf16x8 p2 = *(const bf16x8*)&Opart[base0 + 2 * SSTR];
        bf16x8 p3 = *(const bf16x8*)&Opart[base0 + 3 * SSTR];
        const float rl = linv[head];
        float p[8];
#pragma unroll
        for (int j = 0; j < 8; ++j) {
            p[j] = (bf16_to_f32((unsigned short)p0[j]) + bf16_to_f32((unsigned short)p1[j]) +
                    bf16_to_f32((unsigned short)p2[j]) + bf16_to_f32((unsigned short)p3[j])) * rl;
        }
        uint4 pk;
        pk.x = pack_rnd(p[0], p[1]);
        pk.y = pack_rnd(p[2], p[3]);
        pk.z = pack_rnd(p[4], p[5]);
        pk.w = pack_rnd(p[6], p[7]);
        bf16x8 bfv = __builtin_bit_cast(bf16x8, pk);
        bf16x8 af = *(const bf16x8*)&OWsw[abase + kc * 512];
        acc = __builtin_amdgcn_mfma_f32_32x32x16_bf16(af, bfv, acc, 0, 0, 0);
    }

    const size_t base = (size_t)b * C_DIM * N_DIM;
    float gs[4], gq[4];
#pragma unroll
    for (int j = 0; j < 4; ++j) { gs[j] = 0.f; gq[j] = 0.f; }
#pragma unroll
    for (int r = 0; r < 16; ++r) {
        const int o = o0 + (r & 3) + 8 * (r >> 2) + 4 * q2;
        const size_t addr = base + (size_t)o * N_DIM + n;
        const float v = acc[r] + ob[o] + query[addr];
        y16[addr] = f32_to_bf16(v);
        gs[r >> 2] += v;
        gq[r >> 2] += v * v;
    }
#pragma unroll
    for (int offd = 1; offd < 64; offd <<= 1) {
#pragma unroll
        for (int j = 0; j < 4; ++j) {
            gs[j] += __shfl_xor(gs[j], offd, 64);
            gq[j] += __shfl_xor(gq[j], offd, 64);
        }
    }
    if (lane == 0) {
#pragma unroll
        for (int j = 0; j < 4; ++j) {
            const int grp = oz * 16 + w * 4 + j;
            const size_t slot = ((size_t)(b * 32 + grp) * 128 + blockIdx.x) * 2;
            pstats[slot + 0] = gs[j];
            pstats[slot + 1] = gq[j];
        }
    }
}

// ---------------------------------------------------------------------------
// GroupNorm apply: wave 0 sums the group's 128 partial pairs, block applies.
// Final d_out stores are nontemporal (never re-read; keep y16 in L2).
// ---------------------------------------------------------------------------
__global__ __launch_bounds__(256) void gn_apply(
    const short* __restrict__ y16, const float* __restrict__ pstats,
    const float* __restrict__ gw, const float* __restrict__ gb,
    float* __restrict__ out)
{
    const int g = blockIdx.x, b = blockIdx.y, sl = blockIdx.z;
    const int t = threadIdx.x;
    __shared__ float sh[2];
    if (t < 64) {
        const size_t pb = (size_t)(b * 32 + g) * 128;
        float s = 0.f, qq = 0.f;
#pragma unroll
        for (int i = 0; i < 2; ++i) {
            float2 p = *(const float2*)&pstats[(pb + t + i * 64) * 2];
            s += p.x; qq += p.y;
        }
#pragma unroll
        for (int off = 1; off < 64; off <<= 1) {
            s  += __shfl_xor(s, off, 64);
            qq += __shfl_xor(qq, off, 64);
        }
        if (t == 0) {
            const float mean = s * (1.f / 32768.f);
            const float var  = qq * (1.f / 32768.f) - mean * mean;
            sh[0] = mean;
            sh[1] = rsqrtf(var + 1e-5f);
        }
    }
    __syncthreads();
    const float mean = sh[0], rstd = sh[1];

    const size_t base = ((size_t)b * C_DIM + (size_t)g * 8) * N_DIM + sl * 1024;
#pragma unroll
    for (int i = 0; i < 8; ++i) {
        const int idx = t + i * 256;
        const int row = idx >> 8, col = (idx & 255) * 4;
        const size_t a = base + (size_t)row * N_DIM + col;
        const float wv  = gw[g * 8 + row] * rstd;
        const float bb2 = gb[g * 8 + row];
        ushort4 u = *(const ushort4*)&y16[a];
        f32x4v v;
        v.x = (bf16_to_f32(u.x) - mean) * wv + bb2;
        v.y = (bf16_to_f32(u.y) - mean) * wv + bb2;
        v.z = (bf16_to_f32(u.z) - mean) * wv + bb2;
        v.w = (bf16_to_f32(u.w) - mean) * wv + bb2;
        __builtin_nontemporal_store(v, (f32x4v*)&out[a]);
    }
}

// ---------------------------------------------------------------------------
extern "C" void kernel_launch(void* const* d_in, const int* in_sizes, int n_in,
                              void* d_out, int out_size, void* d_ws, size_t ws_size,
                              hipStream_t stream)
{
    const float* query = (const float*)d_in[0];
    const float* key   = (const float*)d_in[1];
    const float* q_w   = (const float*)d_in[2];
    const float* q_b   = (const float*)d_in[3];
    const float* k_w   = (const float*)d_in[4];
    const float* k_b   = (const float*)d_in[5];
    const float* v_w   = (const float*)d_in[6];
    const float* v_b   = (const float*)d_in[7];
    const float* o_w   = (const float*)d_in[8];
    const float* o_b   = (const float*)d_in[9];
    const float* gn_w  = (const float*)d_in[10];
    const float* gn_b  = (const float*)d_in[11];

    // ws (MiB): [0,0.5) Wsw  [0.5..) pstats(64KB)  [1,5) Qx  [5,9) Kx
    // [9,13) Qt  [13,17) Kt  [17,21) Vt  [21,37) Opart  [37,38) lpart
    // y16 aliases Qx (dead after qkv_gemm).
    char* wsb = (char*)d_ws;
    short* Wsw   = (short*)wsb;
    float* pstats= (float*)(wsb + (1u << 19));
    short* Qx    = (short*)(wsb + (1u  << 20));
    short* Kx    = (short*)(wsb + (5u  << 20));
    short* Qt    = (short*)(wsb + (9u  << 20));
    short* Kt    = (short*)(wsb + (13u << 20));
    short* Vt    = (short*)(wsb + (17u << 20));
    short* Opart = (short*)(wsb + (21u << 20));
    float* lpart = (float*)(wsb + (37u << 20));
    short* y16   = Qx;

    // softmax scale 1/sqrt(32) * log2(e), folded into Q projection
    const float qscale = 0.17677669529663687f * 1.4426950408889634f;

    prep<<<dim3(64, 4, 5), 256, 0, stream>>>(query, key, q_w, k_w, v_w, o_w,
                                             Qx, Kx, Wsw);
    qkv_gemm<<<dim3(64, 4, 6), 256, 0, stream>>>(Wsw, Qx, Kx, q_b, k_b, v_b,
                                                 Qt, Kt, Vt, qscale);
    flash_mfma<<<dim3(32, 8, 8), 256, 0, stream>>>(Qt, Kt, Vt, Opart, lpart);
    out_gemm<<<dim3(128, 2, 2), 256, 0, stream>>>(Wsw + 3 * 65536, Opart, lpart,
                                                  o_b, query, y16, pstats);
    gn_apply<<<dim3(32, 2, 4), 256, 0, stream>>>(y16, pstats, gn_w, gn_b,
                                                 (float*)d_out);
}

// Round 17
// 164.071 us; speedup vs baseline: 1.0163x; 1.0163x over previous
//
#include <hip/hip_runtime.h>
#include <math.h>

#define C_DIM 256
#define N_DIM 4096
#define NHEAD 8

using bf16x8 = __attribute__((ext_vector_type(8))) short;   // 8 bf16 = 4 VGPRs
using f32x16 = __attribute__((ext_vector_type(16))) float;  // 32x32 MFMA acc

__device__ __forceinline__ short f32_to_bf16(float a) {
    return (short)((__float_as_uint(a) + 0x8000u) >> 16);
}
__device__ __forceinline__ float bf16_to_f32(unsigned short u) {
    return __uint_as_float(((unsigned)u) << 16);
}
// truncating pack: lo = hi16(a), hi = hi16(b)
__device__ __forceinline__ unsigned pack_trunc(float a, float b) {
    return __builtin_amdgcn_perm(__float_as_uint(b), __float_as_uint(a), 0x07060302u);
}
// rounded pack: lo = bf16_rnd(a), hi = bf16_rnd(b)  (same bits as f32_to_bf16)
__device__ __forceinline__ unsigned pack_rnd(float a, float b) {
    return __builtin_amdgcn_perm(__float_as_uint(b) + 0x8000u,
                                 __float_as_uint(a) + 0x8000u, 0x07060302u);
}

// Fragment-order ("swizzled") layout for 256-col planes, index in shorts.
// Per 32-row tile: [16 kc][2 q2][32 row][8 c]
__device__ __forceinline__ int SWZ(int m, int c) {
    return (m >> 5) * 8192 + (c >> 4) * 512 + ((c >> 3) & 1) * 256 + (m & 31) * 8 + (c & 7);
}

// ---------------------------------------------------------------------------
// prep: z<4 -> transpose query/key [c][n] fp32 -> swizzled bf16 [n][c] planes
//       z==4 -> convert 4 weight planes fp32 -> swizzled bf16
// ---------------------------------------------------------------------------
__global__ __launch_bounds__(256) void prep(
    const float* __restrict__ query, const float* __restrict__ key,
    const float* __restrict__ qw, const float* __restrict__ kw,
    const float* __restrict__ vw, const float* __restrict__ ow,
    short* __restrict__ Qx, short* __restrict__ Kx, short* __restrict__ Wsw)
{
    const int t = threadIdx.x;
    if (blockIdx.z == 4) {
        const int p = blockIdx.y;
        const float* src = (p == 0) ? qw : (p == 1) ? kw : (p == 2) ? vw : ow;
        const int idx = (blockIdx.x * 256 + t) * 4;
        const int o = idx >> 8, c = idx & 255;
        float4 v = *(const float4*)&src[idx];
        short* dst = Wsw + p * 65536 + SWZ(o, c);
        dst[0] = f32_to_bf16(v.x); dst[1] = f32_to_bf16(v.y);
        dst[2] = f32_to_bf16(v.z); dst[3] = f32_to_bf16(v.w);
        return;
    }
    __shared__ unsigned Ts32[32][33];   // [n-local][c-pair], pitch 33 words
    const int z = blockIdx.z;
    const float* in = (z < 2) ? query : key;
    short* out = ((z < 2) ? Qx : Kx) + (size_t)(z & 1) * N_DIM * C_DIM;
    const size_t ibase = (size_t)(z & 1) * C_DIM * N_DIM;
    const int n0 = blockIdx.x * 64, c0 = blockIdx.y * 64;
    const int cp = t >> 3, ng = t & 7;   // c-pair 0..31, n-group 0..7

#pragma unroll
    for (int h2 = 0; h2 < 2; ++h2) {
        const int nb = h2 * 32 + ng * 4;
        float4 a = *(const float4*)&in[ibase + (size_t)(c0 + 2 * cp) * N_DIM + n0 + nb];
        float4 b = *(const float4*)&in[ibase + (size_t)(c0 + 2 * cp + 1) * N_DIM + n0 + nb];
        Ts32[ng * 4 + 0][cp] = pack_rnd(a.x, b.x);
        Ts32[ng * 4 + 1][cp] = pack_rnd(a.y, b.y);
        Ts32[ng * 4 + 2][cp] = pack_rnd(a.z, b.z);
        Ts32[ng * 4 + 3][cp] = pack_rnd(a.w, b.w);
        __syncthreads();
        const int nl = t >> 3, cg = t & 7;
        uint4 val;
        val.x = Ts32[nl][cg * 4 + 0];
        val.y = Ts32[nl][cg * 4 + 1];
        val.z = Ts32[nl][cg * 4 + 2];
        val.w = Ts32[nl][cg * 4 + 3];
        *(uint4*)&out[SWZ(n0 + h2 * 32 + nl, c0 + cg * 8)] = val;
        __syncthreads();
    }
}

// ---------------------------------------------------------------------------
// QKV projection: operand-swapped C-tiles, b64 fragment-order epilogue
// stores (verified r12-r14).
// ---------------------------------------------------------------------------
__global__ __launch_bounds__(256) void qkv_gemm(
    const short* __restrict__ Wsw, const short* __restrict__ Qx,
    const short* __restrict__ Kx,
    const float* __restrict__ q_b, const float* __restrict__ k_b,
    const float* __restrict__ v_b,
    short* __restrict__ Qt, short* __restrict__ Kt, short* __restrict__ Vt,
    float qscale)
{
    const int t = threadIdx.x, w = t >> 6, lane = t & 63;
    const int q2 = lane >> 5, l31 = lane & 31;
    const int proj = blockIdx.z >> 1, b = blockIdx.z & 1;
    const int n0 = blockIdx.x * 64 + (w >> 1) * 32;
    const int o0 = blockIdx.y * 64 + (w & 1) * 32;
    const short* X = ((proj == 0) ? Qx : Kx) + (size_t)b * N_DIM * C_DIM;
    const short* W = Wsw + proj * 65536;
    const float* bias = (proj == 0) ? q_b : (proj == 1) ? k_b : v_b;
    const int xbase = (n0 >> 5) * 8192 + q2 * 256 + l31 * 8;
    const int wbase = (o0 >> 5) * 8192 + q2 * 256 + l31 * 8;

    f32x16 acc;
#pragma unroll
    for (int r = 0; r < 16; ++r) acc[r] = 0.f;

#pragma unroll 4
    for (int kc = 0; kc < C_DIM; kc += 16) {
        bf16x8 xf = *(const bf16x8*)&X[xbase + (kc >> 4) * 512];
        bf16x8 wf = *(const bf16x8*)&W[wbase + (kc >> 4) * 512];
        if (proj == 2)
            acc = __builtin_amdgcn_mfma_f32_32x32x16_bf16(xf, wf, acc, 0, 0, 0);
        else
            acc = __builtin_amdgcn_mfma_f32_32x32x16_bf16(wf, xf, acc, 0, 0, 0);
    }

    const int head = o0 >> 5;
    const size_t fbase = (size_t)(n0 >> 5) * 1024 + l31 * 8 + 4 * q2;
    if (proj < 2) {
        short* OH = ((proj == 0) ? Qt : Kt) + (size_t)(b * NHEAD + head) * N_DIM * 32;
        const float sc = (proj == 0) ? qscale : 1.f;
#pragma unroll
        for (int g = 0; g < 4; ++g) {
            float4 bv = *(const float4*)&bias[o0 + 8 * g + 4 * q2];
            uint2 st;
            st.x = pack_rnd((acc[4 * g + 0] + bv.x) * sc, (acc[4 * g + 1] + bv.y) * sc);
            st.y = pack_rnd((acc[4 * g + 2] + bv.z) * sc, (acc[4 * g + 3] + bv.w) * sc);
            *(uint2*)&OH[fbase + (g >> 1) * 512 + (g & 1) * 256] = st;
        }
    } else {
        short* VH = Vt + (size_t)(b * NHEAD + head) * N_DIM * 32;
        const float bi = bias[o0 + l31];
#pragma unroll
        for (int g = 0; g < 4; ++g) {
            uint2 st;
            st.x = pack_rnd(acc[4 * g + 0] + bi, acc[4 * g + 1] + bi);
            st.y = pack_rnd(acc[4 * g + 2] + bi, acc[4 * g + 3] + bi);
            *(uint2*)&VH[fbase + (g >> 1) * 512 + (g & 1) * 256] = st;
        }
    }
}

// ---------------------------------------------------------------------------
// Flash attention (verified r14, ~59.8 us): zc hoisted, shfl+cndmask P^T
// routing (44 VGPR — the permlane variant cost occupancy, r16), fragment-
// order Opart epilogue.
// ---------------------------------------------------------------------------
__global__ __launch_bounds__(256) void flash_mfma(
    const short* __restrict__ Qt, const short* __restrict__ Kt,
    const short* __restrict__ Vt, short* __restrict__ Opart,
    float* __restrict__ lpart)
{
    const int n0 = blockIdx.x * 128;
    const int h  = blockIdx.y;
    const int z  = blockIdx.z;
    const int b  = z >> 2, s = z & 3;
    const int CHUNK = N_DIM / 4;
    const int t = threadIdx.x, w = t >> 6, lane = t & 63;
    const int q2 = lane >> 5, l31 = lane & 31;
    const int q  = n0 + w * 32 + l31;
    const int bhp = b * NHEAD + h;
    const size_t hb = (size_t)bhp * N_DIM * 32;

    const int qoff = (q >> 5) * 1024 + q2 * 256 + (q & 31) * 8;
    bf16x8 Qf0 = *(const bf16x8*)&Qt[hb + qoff];
    bf16x8 Qf1 = *(const bf16x8*)&Qt[hb + qoff + 512];

    const f32x16 zc = {};   // hoisted zero-C (constant across the K loop)

    int off = ((s * CHUNK) >> 5) * 1024 + q2 * 256 + l31 * 8;
    bf16x8 Kc0 = *(const bf16x8*)&Kt[hb + off];
    bf16x8 Kc1 = *(const bf16x8*)&Kt[hb + off + 512];
    bf16x8 Vc0 = *(const bf16x8*)&Vt[hb + off];
    bf16x8 Vc1 = *(const bf16x8*)&Vt[hb + off + 512];
    off += 1024;

    f32x16 Of;
#pragma unroll
    for (int r = 0; r < 16; ++r) Of[r] = 0.f;
    float ls = 0.f;

    for (int it = 0; it < CHUNK / 32; ++it) {
        bf16x8 Kn0 = *(const bf16x8*)&Kt[hb + off];
        bf16x8 Kn1 = *(const bf16x8*)&Kt[hb + off + 512];
        bf16x8 Vn0 = *(const bf16x8*)&Vt[hb + off];
        bf16x8 Vn1 = *(const bf16x8*)&Vt[hb + off + 512];
        off += 1024;

        f32x16 acc = __builtin_amdgcn_mfma_f32_32x32x16_bf16(Kc0, Qf0, zc, 0, 0, 0);
        acc = __builtin_amdgcn_mfma_f32_32x32x16_bf16(Kc1, Qf1, acc, 0, 0, 0);

        float p[16];
#pragma unroll
        for (int r = 0; r < 16; ++r) { p[r] = __builtin_amdgcn_exp2f(acc[r]); ls += p[r]; }

        unsigned u[8], xu[8];
#pragma unroll
        for (int g = 0; g < 8; ++g) u[g] = pack_trunc(p[2 * g], p[2 * g + 1]);
#pragma unroll
        for (int g = 0; g < 8; ++g) xu[g] = (unsigned)__shfl_xor((int)u[g], 32, 64);

        uint4 f0, f1;
        f0.x = q2 ? xu[2] : u[0];  f0.y = q2 ? xu[3] : u[1];
        f0.z = q2 ? u[2]  : xu[0]; f0.w = q2 ? u[3]  : xu[1];
        f1.x = q2 ? xu[6] : u[4];  f1.y = q2 ? xu[7] : u[5];
        f1.z = q2 ? u[6]  : xu[4]; f1.w = q2 ? u[7]  : xu[5];
        bf16x8 Pf0 = __builtin_bit_cast(bf16x8, f0);
        bf16x8 Pf1 = __builtin_bit_cast(bf16x8, f1);

        Of = __builtin_amdgcn_mfma_f32_32x32x16_bf16(Vc0, Pf0, Of, 0, 0, 0);
        Of = __builtin_amdgcn_mfma_f32_32x32x16_bf16(Vc1, Pf1, Of, 0, 0, 0);

        Kc0 = Kn0; Kc1 = Kn1; Vc0 = Vn0; Vc1 = Vn1;
    }

    ls += __shfl_xor(ls, 32, 64);

    // Opart in fragment order: reg group g holds d = 8g+4q2 .. +3 for row q.
    const size_t obase = (size_t)(s * 16 + bhp) * (N_DIM * 32)
                       + (size_t)(q >> 5) * 1024 + l31 * 8 + 4 * q2;
#pragma unroll
    for (int g = 0; g < 4; ++g) {
        uint2 st;
        st.x = pack_rnd(Of[4 * g + 0], Of[4 * g + 1]);
        st.y = pack_rnd(Of[4 * g + 2], Of[4 * g + 3]);
        *(uint2*)&Opart[obase + (g >> 1) * 512 + (g & 1) * 256] = st;
    }
    lpart[(size_t)(s * 16 + bhp) * N_DIM + q] = ls;
}

// ---------------------------------------------------------------------------
// Out projection with fused split-K combine + fused GroupNorm partial stats
// (verified r14).
// ---------------------------------------------------------------------------
__global__ __launch_bounds__(256) void out_gemm(
    const short* __restrict__ OWsw, const short* __restrict__ Opart,
    const float* __restrict__ lpart, const float* __restrict__ ob,
    const float* __restrict__ query, short* __restrict__ y16,
    float* __restrict__ pstats)
{
    const int t = threadIdx.x, w = t >> 6, lane = t & 63;
    const int q2 = lane >> 5, l31 = lane & 31;
    const int n0 = blockIdx.x * 32, b = blockIdx.y, oz = blockIdx.z;
    const int o0 = oz * 128 + w * 32;
    const int n = n0 + l31;

    float linv[8];
#pragma unroll
    for (int h = 0; h < 8; ++h) {
        float s = 0.f;
#pragma unroll
        for (int s4 = 0; s4 < 4; ++s4)
            s += lpart[(size_t)(s4 * 16 + b * 8 + h) * N_DIM + n];
        linv[h] = 1.f / s;
    }

    const int abase = (o0 >> 5) * 8192 + q2 * 256 + l31 * 8;
    const size_t SSTR = (size_t)16 * N_DIM * 32;

    f32x16 acc;
#pragma unroll
    for (int r = 0; r < 16; ++r) acc[r] = 0.f;

#pragma unroll
    for (int kc = 0; kc < 16; ++kc) {
        const int head = kc >> 1;
        const size_t base0 = (size_t)(b * 8 + head) * (N_DIM * 32)
                           + (size_t)(n0 >> 5) * 1024 + (kc & 1) * 512
                           + q2 * 256 + l31 * 8;
        bf16x8 p0 = *(const bf16x8*)&Opart[base0];
        bf16x8 p1 = *(const bf16x8*)&Opart[base0 + SSTR];
        bf16x8 p2 = *(const bf16x8*)&Opart[base0 + 2 * SSTR];
        bf16x8 p3 = *(const bf16x8*)&Opart[base0 + 3 * SSTR];
        const float rl = linv[head];
        float p[8];
#pragma unroll
        for (int j = 0; j < 8; ++j) {
            p[j] = (bf16_to_f32((unsigned short)p0[j]) + bf16_to_f32((unsigned short)p1[j]) +
                    bf16_to_f32((unsigned short)p2[j]) + bf16_to_f32((unsigned short)p3[j])) * rl;
        }
        uint4 pk;
        pk.x = pack_rnd(p[0], p[1]);
        pk.y = pack_rnd(p[2], p[3]);
        pk.z = pack_rnd(p[4], p[5]);
        pk.w = pack_rnd(p[6], p[7]);
        bf16x8 bfv = __builtin_bit_cast(bf16x8, pk);
        bf16x8 af = *(const bf16x8*)&OWsw[abase + kc * 512];
        acc = __builtin_amdgcn_mfma_f32_32x32x16_bf16(af, bfv, acc, 0, 0, 0);
    }

    const size_t base = (size_t)b * C_DIM * N_DIM;
    float gs[4], gq[4];
#pragma unroll
    for (int j = 0; j < 4; ++j) { gs[j] = 0.f; gq[j] = 0.f; }
#pragma unroll
    for (int r = 0; r < 16; ++r) {
        const int o = o0 + (r & 3) + 8 * (r >> 2) + 4 * q2;
        const size_t addr = base + (size_t)o * N_DIM + n;
        const float v = acc[r] + ob[o] + query[addr];
        y16[addr] = f32_to_bf16(v);
        gs[r >> 2] += v;
        gq[r >> 2] += v * v;
    }
#pragma unroll
    for (int offd = 1; offd < 64; offd <<= 1) {
#pragma unroll
        for (int j = 0; j < 4; ++j) {
            gs[j] += __shfl_xor(gs[j], offd, 64);
            gq[j] += __shfl_xor(gq[j], offd, 64);
        }
    }
    if (lane == 0) {
#pragma unroll
        for (int j = 0; j < 4; ++j) {
            const int grp = oz * 16 + w * 4 + j;
            const size_t slot = ((size_t)(b * 32 + grp) * 128 + blockIdx.x) * 2;
            pstats[slot + 0] = gs[j];
            pstats[slot + 1] = gq[j];
        }
    }
}

// ---------------------------------------------------------------------------
// GroupNorm apply: wave 0 sums the group's 128 partial pairs, block applies.
// (verified r14 — plain stores; NT-store experiment was confounded, r16)
// ---------------------------------------------------------------------------
__global__ __launch_bounds__(256) void gn_apply(
    const short* __restrict__ y16, const float* __restrict__ pstats,
    const float* __restrict__ gw, const float* __restrict__ gb,
    float* __restrict__ out)
{
    const int g = blockIdx.x, b = blockIdx.y, sl = blockIdx.z;
    const int t = threadIdx.x;
    __shared__ float sh[2];
    if (t < 64) {
        const size_t pb = (size_t)(b * 32 + g) * 128;
        float s = 0.f, qq = 0.f;
#pragma unroll
        for (int i = 0; i < 2; ++i) {
            float2 p = *(const float2*)&pstats[(pb + t + i * 64) * 2];
            s += p.x; qq += p.y;
        }
#pragma unroll
        for (int off = 1; off < 64; off <<= 1) {
            s  += __shfl_xor(s, off, 64);
            qq += __shfl_xor(qq, off, 64);
        }
        if (t == 0) {
            const float mean = s * (1.f / 32768.f);
            const float var  = qq * (1.f / 32768.f) - mean * mean;
            sh[0] = mean;
            sh[1] = rsqrtf(var + 1e-5f);
        }
    }
    __syncthreads();
    const float mean = sh[0], rstd = sh[1];

    const size_t base = ((size_t)b * C_DIM + (size_t)g * 8) * N_DIM + sl * 1024;
#pragma unroll
    for (int i = 0; i < 8; ++i) {
        const int idx = t + i * 256;
        const int row = idx >> 8, col = (idx & 255) * 4;
        const size_t a = base + (size_t)row * N_DIM + col;
        const float wv  = gw[g * 8 + row] * rstd;
        const float bb2 = gb[g * 8 + row];
        ushort4 u = *(const ushort4*)&y16[a];
        float4 v;
        v.x = (bf16_to_f32(u.x) - mean) * wv + bb2;
        v.y = (bf16_to_f32(u.y) - mean) * wv + bb2;
        v.z = (bf16_to_f32(u.z) - mean) * wv + bb2;
        v.w = (bf16_to_f32(u.w) - mean) * wv + bb2;
        *(float4*)&out[a] = v;
    }
}

// ---------------------------------------------------------------------------
extern "C" void kernel_launch(void* const* d_in, const int* in_sizes, int n_in,
                              void* d_out, int out_size, void* d_ws, size_t ws_size,
                              hipStream_t stream)
{
    const float* query = (const float*)d_in[0];
    const float* key   = (const float*)d_in[1];
    const float* q_w   = (const float*)d_in[2];
    const float* q_b   = (const float*)d_in[3];
    const float* k_w   = (const float*)d_in[4];
    const float* k_b   = (const float*)d_in[5];
    const float* v_w   = (const float*)d_in[6];
    const float* v_b   = (const float*)d_in[7];
    const float* o_w   = (const float*)d_in[8];
    const float* o_b   = (const float*)d_in[9];
    const float* gn_w  = (const float*)d_in[10];
    const float* gn_b  = (const float*)d_in[11];

    // ws (MiB): [0,0.5) Wsw  [0.5..) pstats(64KB)  [1,5) Qx  [5,9) Kx
    // [9,13) Qt  [13,17) Kt  [17,21) Vt  [21,37) Opart  [37,38) lpart
    // y16 aliases Qx (dead after qkv_gemm).
    char* wsb = (char*)d_ws;
    short* Wsw   = (short*)wsb;
    float* pstats= (float*)(wsb + (1u << 19));
    short* Qx    = (short*)(wsb + (1u  << 20));
    short* Kx    = (short*)(wsb + (5u  << 20));
    short* Qt    = (short*)(wsb + (9u  << 20));
    short* Kt    = (short*)(wsb + (13u << 20));
    short* Vt    = (short*)(wsb + (17u << 20));
    short* Opart = (short*)(wsb + (21u << 20));
    float* lpart = (float*)(wsb + (37u << 20));
    short* y16   = Qx;

    // softmax scale 1/sqrt(32) * log2(e), folded into Q projection
    const float qscale = 0.17677669529663687f * 1.4426950408889634f;

    prep<<<dim3(64, 4, 5), 256, 0, stream>>>(query, key, q_w, k_w, v_w, o_w,
                                             Qx, Kx, Wsw);
    qkv_gemm<<<dim3(64, 4, 6), 256, 0, stream>>>(Wsw, Qx, Kx, q_b, k_b, v_b,
                                                 Qt, Kt, Vt, qscale);
    flash_mfma<<<dim3(32, 8, 8), 256, 0, stream>>>(Qt, Kt, Vt, Opart, lpart);
    out_gemm<<<dim3(128, 2, 2), 256, 0, stream>>>(Wsw + 3 * 65536, Opart, lpart,
                                                  o_b, query, y16, pstats);
    gn_apply<<<dim3(32, 2, 4), 256, 0, stream>>>(y16, pstats, gn_w, gn_b,
                                                 (float*)d_out);
}